// Round 3
// baseline (99.610 us; speedup 1.0000x reference)
//
#include <hip/hip_runtime.h>
#include <hip/hip_bf16.h>
#include <math.h>

// Problem constants (static config in reference)
#define NT      4096              // B*T
#define DD      1024              // D
#define EE      8                 // experts
#define KK      2                 // top-k
#define CAP     1280              // EXP_CAP
#define CBN     (NT * EE * CAP)   // 41,943,040 elements per big output
#define NROW    (NT * EE)         // 32768 (t,e) rows
#define F4ROW   (CAP / 4)         // 320 float4 per row
#define CB_F4   (CBN / 4)         // 10,485,760 float4 per section

// LDS index swizzle (involution): spreads per-thread contiguous-32 walks
// across all banks.
__device__ __forceinline__ int swz(int j) { return j ^ ((j >> 5) & 31); }

// ---------------------------------------------------------------------------
// K1: router logits + top-2 + softmax(top-2). Wave per token, w in LDS.
// ---------------------------------------------------------------------------
__global__ __launch_bounds__(256) void logits_kernel(
    const float* __restrict__ x,        // (NT, D)
    const float* __restrict__ w,        // (E, D)
    int* __restrict__ e0, int* __restrict__ e1,
    float* __restrict__ p0, float* __restrict__ p1)
{
    __shared__ float wl[EE * DD];       // 32 KB

    for (int i = threadIdx.x; i < EE * DD / 4; i += 256)
        reinterpret_cast<float4*>(wl)[i] = reinterpret_cast<const float4*>(w)[i];
    __syncthreads();

    const int wave = threadIdx.x >> 6;
    const int lane = threadIdx.x & 63;
    const int wid  = blockIdx.x * 4 + wave;

    for (int t = wid; t < NT; t += gridDim.x * 4) {
        const float4* xt = reinterpret_cast<const float4*>(x + (size_t)t * DD);
        float acc[EE];
        #pragma unroll
        for (int e = 0; e < EE; ++e) acc[e] = 0.0f;

        #pragma unroll
        for (int ii = 0; ii < DD / 4 / 64; ++ii) {      // 4 iters
            const int i = ii * 64 + lane;
            const float4 xv = xt[i];
            #pragma unroll
            for (int e = 0; e < EE; ++e) {
                const float4 wv = reinterpret_cast<const float4*>(wl + e * DD)[i];
                acc[e] += xv.x * wv.x + xv.y * wv.y + xv.z * wv.z + xv.w * wv.w;
            }
        }

        #pragma unroll
        for (int e = 0; e < EE; ++e) {
            float v = acc[e];
            #pragma unroll
            for (int off = 32; off > 0; off >>= 1) v += __shfl_xor(v, off);
            acc[e] = v;
        }

        if (lane == 0) {
            int b0 = 0; float l0 = acc[0];
            #pragma unroll
            for (int e = 1; e < EE; ++e) { if (acc[e] > l0) { l0 = acc[e]; b0 = e; } }
            int b1 = -1; float l1 = -INFINITY;
            #pragma unroll
            for (int e = 0; e < EE; ++e) { if (e != b0 && acc[e] > l1) { l1 = acc[e]; b1 = e; } }

            const float z  = expf(l1 - l0);     // l1 <= l0
            const float pa = 1.0f / (1.0f + z);
            const float pb = z * pa;

            e0[t] = b0; e1[t] = b1;
            p0[t] = pa; p1[t] = pb;
        }
    }
}

// ---------------------------------------------------------------------------
// K2: ordered rank / capacity drop -> dense per-(t,e) table + used_cap.
// One block, 256 threads. Assignment order j = k*NT + t.
// sl[t*8+e] = slot (or -1), val[t*8+e] = softmax weight.
// ---------------------------------------------------------------------------
__global__ __launch_bounds__(256) void rank_table_kernel(
    const int* __restrict__ e0, const int* __restrict__ e1,
    const float* __restrict__ p0, const float* __restrict__ p1,
    int* __restrict__ sl, float* __restrict__ val,
    float* __restrict__ out)
{
    __shared__ int   se[KK * NT];       // 32 KB, swizzled
    __shared__ float sp[KK * NT];       // 32 KB, swizzled
    __shared__ unsigned long long wsumA[4], wsumB[4];

    const int tid = threadIdx.x;

    // init slot table to -1 (unassigned rows)
    int4* sl4 = reinterpret_cast<int4*>(sl);
    const int4 neg = make_int4(-1, -1, -1, -1);
    for (int i = tid; i < NROW / 4; i += 256) sl4[i] = neg;

    // coalesced stage of assignments
    for (int i = tid; i < NT; i += 256) {
        se[swz(i)]      = e0[i];
        se[swz(NT + i)] = e1[i];
        sp[swz(i)]      = p0[i];
        sp[swz(NT + i)] = p1[i];
    }
    __syncthreads();

    const int base = tid * 32;
    unsigned long long ca = 0ull, cb = 0ull;    // experts 0-3 / 4-7, 16b fields
    #pragma unroll
    for (int i = 0; i < 32; ++i) {
        const int e = se[swz(base + i)];
        if (e < 4) ca += 1ull << (16 * e);
        else       cb += 1ull << (16 * (e - 4));
    }

    // intra-wave inclusive scan
    unsigned long long sa = ca, sb = cb;
    #pragma unroll
    for (int off = 1; off < 64; off <<= 1) {
        const unsigned long long ta = __shfl_up(sa, off);
        const unsigned long long tb = __shfl_up(sb, off);
        if ((tid & 63) >= off) { sa += ta; sb += tb; }
    }
    const int wv = tid >> 6;
    if ((tid & 63) == 63) { wsumA[wv] = sa; wsumB[wv] = sb; }
    __syncthreads();

    unsigned long long preA = 0ull, preB = 0ull;
    #pragma unroll
    for (int k = 0; k < 4; ++k) {
        if (k < wv) { preA += wsumA[k]; preB += wsumB[k]; }
    }
    unsigned long long ra = preA + sa - ca;     // exclusive prefix
    unsigned long long rb = preB + sb - cb;

    // replay in ascending j order; fill tables
    #pragma unroll
    for (int i = 0; i < 32; ++i) {
        const int j = base + i;
        const int e = se[swz(j)];
        int rank;
        if (e < 4) { rank = (int)((ra >> (16 * e)) & 0xFFFF);       ra += 1ull << (16 * e); }
        else       { rank = (int)((rb >> (16 * (e - 4))) & 0xFFFF); rb += 1ull << (16 * (e - 4)); }
        if (rank < CAP) {
            const int t = j & (NT - 1);
            sl[t * EE + e]  = rank;
            val[t * EE + e] = sp[swz(j)];
        }
    }

    // used_cap
    if (tid < EE) {
        const unsigned long long totA = wsumA[0] + wsumA[1] + wsumA[2] + wsumA[3];
        const unsigned long long totB = wsumB[0] + wsumB[1] + wsumB[2] + wsumB[3];
        const int e = tid;
        const int tot = (e < 4) ? (int)((totA >> (16 * e)) & 0xFFFF)
                                : (int)((totB >> (16 * (e - 4))) & 0xFFFF);
        out[e] = (float)((tot < CAP) ? tot : CAP);
    }
}

// ---------------------------------------------------------------------------
// K3: single streaming write pass producing FINAL values for both sections.
// Each float4 chunk: row r = i/320 -> (t,e); compare slot against c range.
// Table reads are L2/L3-resident (256 KB); stores are pure coalesced streams.
// ---------------------------------------------------------------------------
__global__ __launch_bounds__(256) void write_kernel(
    const int* __restrict__ sl, const float* __restrict__ val,
    float* __restrict__ out)
{
    float4* cb = reinterpret_cast<float4*>(out + 8);
    float4* mk = reinterpret_cast<float4*>(out + 8 + (size_t)CBN);

    int i = blockIdx.x * 256 + threadIdx.x;
    const int stride = gridDim.x * 256;
    for (; i < CB_F4; i += stride) {
        const int r  = i / F4ROW;               // t*8 + e
        const int c0 = (i - r * F4ROW) * 4;
        const int s  = sl[r];
        const float p = val[r];
        const bool on = (p != 0.0f);

        float4 v, m;
        const bool h0 = on && (s == c0);
        const bool h1 = on && (s == c0 + 1);
        const bool h2 = on && (s == c0 + 2);
        const bool h3 = on && (s == c0 + 3);
        v.x = h0 ? p : 0.0f;  m.x = h0 ? 1.0f : 0.0f;
        v.y = h1 ? p : 0.0f;  m.y = h1 ? 1.0f : 0.0f;
        v.z = h2 ? p : 0.0f;  m.z = h2 ? 1.0f : 0.0f;
        v.w = h3 ? p : 0.0f;  m.w = h3 ? 1.0f : 0.0f;

        cb[i] = v;
        mk[i] = m;
    }
}

// ---------------------------------------------------------------------------
extern "C" void kernel_launch(void* const* d_in, const int* in_sizes, int n_in,
                              void* d_out, int out_size, void* d_ws, size_t ws_size,
                              hipStream_t stream) {
    const float* x = (const float*)d_in[0];     // (B,T,D) f32
    const float* w = (const float*)d_in[1];     // (E,D)   f32
    float* out = (float*)d_out;

    char* ws = (char*)d_ws;
    int*   e0  = (int*)(ws);                    // 16 KB
    int*   e1  = (int*)(ws + 16 * 1024);        // 16 KB
    float* p0  = (float*)(ws + 32 * 1024);      // 16 KB
    float* p1  = (float*)(ws + 48 * 1024);      // 16 KB
    int*   sl  = (int*)(ws + 64 * 1024);        // 128 KB (NROW ints)
    float* val = (float*)(ws + 192 * 1024);     // 128 KB (NROW floats)

    // K1: logits/top2/softmax (~4 us)
    logits_kernel<<<256, 256, 0, stream>>>(x, w, e0, e1, p0, p1);

    // K2: ordered rank -> slot/value tables + used_cap (~4 us)
    rank_table_kernel<<<1, 256, 0, stream>>>(e0, e1, p0, p1, sl, val, out);

    // K3: single fill-rate streaming pass writing final output (~50 us)
    write_kernel<<<2048, 256, 0, stream>>>(sl, val, out);
}

// Round 4
// 96.358 us; speedup vs baseline: 1.0338x; 1.0338x over previous
//
#include <hip/hip_runtime.h>
#include <hip/hip_bf16.h>
#include <math.h>

// Problem constants (static config in reference)
#define NT      4096              // B*T
#define DD      1024              // D
#define EE      8                 // experts
#define KK      2                 // top-k
#define CAP     1280              // EXP_CAP
#define CBN     (NT * EE * CAP)   // 41,943,040 elements per big output
#define NROW    (NT * EE)         // 32768 (t,e) rows per section
#define F4ROW   (CAP / 4)         // 320 float4 per row
#define VROWS   (2 * NROW)        // 65536 virtual rows (weights ++ mask)

// LDS index swizzle (involution): spreads per-thread contiguous-32 walks
// across all banks.
__device__ __forceinline__ int swz(int j) { return j ^ ((j >> 5) & 31); }

// ---------------------------------------------------------------------------
// K1: router logits + top-2 + softmax(top-2). Wave per token, w in LDS.
// ---------------------------------------------------------------------------
__global__ __launch_bounds__(256) void logits_kernel(
    const float* __restrict__ x,        // (NT, D)
    const float* __restrict__ w,        // (E, D)
    int* __restrict__ e0, int* __restrict__ e1,
    float* __restrict__ p0, float* __restrict__ p1)
{
    __shared__ float wl[EE * DD];       // 32 KB

    for (int i = threadIdx.x; i < EE * DD / 4; i += 256)
        reinterpret_cast<float4*>(wl)[i] = reinterpret_cast<const float4*>(w)[i];
    __syncthreads();

    const int wave = threadIdx.x >> 6;
    const int lane = threadIdx.x & 63;
    const int wid  = blockIdx.x * 4 + wave;

    for (int t = wid; t < NT; t += gridDim.x * 4) {
        const float4* xt = reinterpret_cast<const float4*>(x + (size_t)t * DD);
        float acc[EE];
        #pragma unroll
        for (int e = 0; e < EE; ++e) acc[e] = 0.0f;

        #pragma unroll
        for (int ii = 0; ii < DD / 4 / 64; ++ii) {      // 4 iters
            const int i = ii * 64 + lane;
            const float4 xv = xt[i];
            #pragma unroll
            for (int e = 0; e < EE; ++e) {
                const float4 wv = reinterpret_cast<const float4*>(wl + e * DD)[i];
                acc[e] += xv.x * wv.x + xv.y * wv.y + xv.z * wv.z + xv.w * wv.w;
            }
        }

        #pragma unroll
        for (int e = 0; e < EE; ++e) {
            float v = acc[e];
            #pragma unroll
            for (int off = 32; off > 0; off >>= 1) v += __shfl_xor(v, off);
            acc[e] = v;
        }

        if (lane == 0) {
            int b0 = 0; float l0 = acc[0];
            #pragma unroll
            for (int e = 1; e < EE; ++e) { if (acc[e] > l0) { l0 = acc[e]; b0 = e; } }
            int b1 = -1; float l1 = -INFINITY;
            #pragma unroll
            for (int e = 0; e < EE; ++e) { if (e != b0 && acc[e] > l1) { l1 = acc[e]; b1 = e; } }

            const float z  = expf(l1 - l0);     // l1 <= l0
            const float pa = 1.0f / (1.0f + z);
            const float pb = z * pa;

            e0[t] = b0; e1[t] = b1;
            p0[t] = pa; p1[t] = pb;
        }
    }
}

// ---------------------------------------------------------------------------
// K2: ordered rank / capacity drop -> dense per-(t,e) table + used_cap.
// One block, 256 threads. Assignment order j = k*NT + t.
// sl[t*8+e] = slot (or -1), val[t*8+e] = softmax weight.
// ---------------------------------------------------------------------------
__global__ __launch_bounds__(256) void rank_table_kernel(
    const int* __restrict__ e0, const int* __restrict__ e1,
    const float* __restrict__ p0, const float* __restrict__ p1,
    int* __restrict__ sl, float* __restrict__ val,
    float* __restrict__ out)
{
    __shared__ int   se[KK * NT];       // 32 KB, swizzled
    __shared__ float sp[KK * NT];       // 32 KB, swizzled
    __shared__ unsigned long long wsumA[4], wsumB[4];

    const int tid = threadIdx.x;

    // init slot table to -1 (unassigned rows)
    int4* sl4 = reinterpret_cast<int4*>(sl);
    const int4 neg = make_int4(-1, -1, -1, -1);
    for (int i = tid; i < NROW / 4; i += 256) sl4[i] = neg;

    // coalesced stage of assignments
    for (int i = tid; i < NT; i += 256) {
        se[swz(i)]      = e0[i];
        se[swz(NT + i)] = e1[i];
        sp[swz(i)]      = p0[i];
        sp[swz(NT + i)] = p1[i];
    }
    __syncthreads();

    const int base = tid * 32;
    unsigned long long ca = 0ull, cb = 0ull;    // experts 0-3 / 4-7, 16b fields
    #pragma unroll
    for (int i = 0; i < 32; ++i) {
        const int e = se[swz(base + i)];
        if (e < 4) ca += 1ull << (16 * e);
        else       cb += 1ull << (16 * (e - 4));
    }

    // intra-wave inclusive scan
    unsigned long long sa = ca, sb = cb;
    #pragma unroll
    for (int off = 1; off < 64; off <<= 1) {
        const unsigned long long ta = __shfl_up(sa, off);
        const unsigned long long tb = __shfl_up(sb, off);
        if ((tid & 63) >= off) { sa += ta; sb += tb; }
    }
    const int wv = tid >> 6;
    if ((tid & 63) == 63) { wsumA[wv] = sa; wsumB[wv] = sb; }
    __syncthreads();

    unsigned long long preA = 0ull, preB = 0ull;
    #pragma unroll
    for (int k = 0; k < 4; ++k) {
        if (k < wv) { preA += wsumA[k]; preB += wsumB[k]; }
    }
    unsigned long long ra = preA + sa - ca;     // exclusive prefix
    unsigned long long rb = preB + sb - cb;

    // replay in ascending j order; fill tables
    #pragma unroll
    for (int i = 0; i < 32; ++i) {
        const int j = base + i;
        const int e = se[swz(j)];
        int rank;
        if (e < 4) { rank = (int)((ra >> (16 * e)) & 0xFFFF);       ra += 1ull << (16 * e); }
        else       { rank = (int)((rb >> (16 * (e - 4))) & 0xFFFF); rb += 1ull << (16 * (e - 4)); }
        if (rank < CAP) {
            const int t = j & (NT - 1);
            sl[t * EE + e]  = rank;
            val[t * EE + e] = sp[swz(j)];
        }
    }

    // used_cap
    if (tid < EE) {
        const unsigned long long totA = wsumA[0] + wsumA[1] + wsumA[2] + wsumA[3];
        const unsigned long long totB = wsumB[0] + wsumB[1] + wsumB[2] + wsumB[3];
        const int e = tid;
        const int tot = (e < 4) ? (int)((totA >> (16 * e)) & 0xFFFF)
                                : (int)((totB >> (16 * (e - 4))) & 0xFFFF);
        out[e] = (float)((tot < CAP) ? tot : CAP);
    }
}

// ---------------------------------------------------------------------------
// K3: fill-isomorphic streaming writer. One wave per 1280-float row.
// Virtual rows 0..65535 cover [weights | mask] contiguously (stride 1280).
// Per row: 2 scalar (wave-uniform) table loads, 5x 1KB coalesced f4 stores.
// No divides, no per-lane table traffic, single linear store stream.
// ---------------------------------------------------------------------------
__global__ __launch_bounds__(256) void write_kernel(
    const int* __restrict__ sl, const float* __restrict__ val,
    float* __restrict__ out)
{
    const int wid  = (blockIdx.x << 2) + (threadIdx.x >> 6);  // 0..16383
    const int lane = threadIdx.x & 63;
    float4* base = reinterpret_cast<float4*>(out + 8);

    #pragma unroll
    for (int rr = 0; rr < 4; ++rr) {
        const int vr = (wid << 2) + rr;                       // virtual row
        const int r  = __builtin_amdgcn_readfirstlane(vr & (NROW - 1));
        const int   s = sl[r];                                // s_load (uniform)
        const float p = val[r];                               // s_load (uniform)
        const bool  on = (s >= 0) && (p != 0.0f);
        const float hv = (vr >= NROW) ? 1.0f : p;             // mask section -> 1.0

        float4* dst = base + (size_t)vr * F4ROW;
        #pragma unroll
        for (int it = 0; it < 5; ++it) {
            const int f4 = (it << 6) + lane;                  // 0..319
            const int c  = f4 << 2;
            float4 v;
            v.x = (on && s == c)     ? hv : 0.0f;
            v.y = (on && s == c + 1) ? hv : 0.0f;
            v.z = (on && s == c + 2) ? hv : 0.0f;
            v.w = (on && s == c + 3) ? hv : 0.0f;
            dst[f4] = v;
        }
    }
}

// ---------------------------------------------------------------------------
extern "C" void kernel_launch(void* const* d_in, const int* in_sizes, int n_in,
                              void* d_out, int out_size, void* d_ws, size_t ws_size,
                              hipStream_t stream) {
    const float* x = (const float*)d_in[0];     // (B,T,D) f32
    const float* w = (const float*)d_in[1];     // (E,D)   f32
    float* out = (float*)d_out;

    char* ws = (char*)d_ws;
    int*   e0  = (int*)(ws);                    // 16 KB
    int*   e1  = (int*)(ws + 16 * 1024);        // 16 KB
    float* p0  = (float*)(ws + 32 * 1024);      // 16 KB
    float* p1  = (float*)(ws + 48 * 1024);      // 16 KB
    int*   sl  = (int*)(ws + 64 * 1024);        // 128 KB (NROW ints)
    float* val = (float*)(ws + 192 * 1024);     // 128 KB (NROW floats)

    // K1: logits/top2/softmax (~4 us)
    logits_kernel<<<256, 256, 0, stream>>>(x, w, e0, e1, p0, p1);

    // K2: ordered rank -> slot/value tables + used_cap (~5 us)
    rank_table_kernel<<<1, 256, 0, stream>>>(e0, e1, p0, p1, sl, val, out);

    // K3: wave-per-row streaming writer, fill-isomorphic (~50 us)
    // 65536 virtual rows / (4 waves/block * 4 rows/wave) = 4096 blocks
    write_kernel<<<4096, 256, 0, stream>>>(sl, val, out);
}